// Round 4
// baseline (162.059 us; speedup 1.0000x reference)
//
#include <hip/hip_runtime.h>
#include <hip/hip_bf16.h>
#include <math.h>

typedef __bf16 bf16;
typedef __attribute__((ext_vector_type(8))) __bf16 bf16x8;
typedef __attribute__((ext_vector_type(4))) __bf16 bf16x4;
typedef __attribute__((ext_vector_type(4))) float f32x4;
typedef __attribute__((ext_vector_type(16))) float f32x16;
typedef __attribute__((ext_vector_type(4))) unsigned int u32x4;

constexpr int NB = 2, NH = 16, SQ = 2048, SKV = 2048, DH = 128;
constexpr int QB = 128, KVB = 32;
constexpr float SM_SCALE = 0.08838834764831845f;  // 1/sqrt(128)
constexpr float LOG2E = 1.4426950408889634f;
constexpr float DEFER_THR = 7.0f;                 // T13: p bounded by e^7

#define GLD_LDS(g, l) __builtin_amdgcn_global_load_lds( \
    (const __attribute__((address_space(1))) void*)(g), \
    (__attribute__((address_space(3))) void*)(l), 16, 0, 0)

// counted vmcnt wait (T4): never drain to 0 in the main loop
#define WAITCNT_VM_(n) asm volatile("s_waitcnt vmcnt(" #n ")" ::: "memory")
#define WAITCNT_VM(n) WAITCNT_VM_(n)

__device__ __forceinline__ unsigned cvt_pk_bf16(float lo, float hi) {
    unsigned r;
    asm("v_cvt_pk_bf16_f32 %0, %1, %2" : "=v"(r) : "v"(lo), "v"(hi));
    return r;
}
// new a[32:63] = old b[0:31]; new b[0:31] = old a[32:63]
__device__ __forceinline__ void permswap(unsigned &a, unsigned &b) {
    asm("v_permlane32_swap_b32 %0, %1" : "+v"(a), "+v"(b));
}

// ---- pre-pass 1: K fp32 -> bf16, layout unchanged [bh][skv][d] ----
__global__ __launch_bounds__(256)
void cvt_k_kernel(const float* __restrict__ src, bf16* __restrict__ dst) {
    const size_t i = ((size_t)blockIdx.x * 256 + threadIdx.x) * 8;
    float4 a = *(const float4*)(src + i);
    float4 b = *(const float4*)(src + i + 4);
    bf16x8 f;
    f[0]=(bf16)a.x; f[1]=(bf16)a.y; f[2]=(bf16)a.z; f[3]=(bf16)a.w;
    f[4]=(bf16)b.x; f[5]=(bf16)b.y; f[6]=(bf16)b.z; f[7]=(bf16)b.w;
    *(bf16x8*)(dst + i) = f;
}

// ---- pre-pass 2: V fp32 [bh][skv][d] -> bf16 transposed [bh][d][skv] ----
__global__ __launch_bounds__(256)
void tr_v_kernel(const float* __restrict__ src, bf16* __restrict__ dst) {
    __shared__ float Tl[64][65];
    const int bh  = blockIdx.y;
    const int kv0 = (int)(blockIdx.x >> 1) * 64;
    const int d0  = (int)(blockIdx.x & 1) * 64;
    const int t   = threadIdx.x;
    const float* sp = src + (size_t)bh * SQ * DH;
#pragma unroll
    for (int i = 0; i < 4; ++i) {
        const int row = i * 16 + (t >> 4);
        const int c4  = (t & 15) * 4;
        *(float4*)&Tl[row][c4] = *(const float4*)(sp + (size_t)(kv0 + row) * DH + d0 + c4);
    }
    __syncthreads();
    bf16* dp = dst + (size_t)bh * DH * SKV;
#pragma unroll
    for (int i = 0; i < 4; ++i) {
        const int d  = i * 16 + (t >> 4);
        const int k4 = (t & 15) * 4;
        bf16x4 o;
        o[0]=(bf16)Tl[k4+0][d]; o[1]=(bf16)Tl[k4+1][d];
        o[2]=(bf16)Tl[k4+2][d]; o[3]=(bf16)Tl[k4+3][d];
        *(bf16x4*)(dp + (size_t)(d0 + d) * SKV + kv0 + k4) = o;
    }
}

// ---- main attention kernel: 32-row waves (32x32x16 MFMA), swapped-QK,
//      in-register P via cvt_pk + permlane32_swap, 4 waves / 256 threads.
//      Sync scheme (this round's change): TRIPLE-buffer LDS, stage tile t+2
//      at top of tile t, raw s_barrier with counted s_waitcnt vmcnt(8/4) --
//      staged loads stay in flight across barriers (never vmcnt(0) in loop).
//      __syncthreads would drain vmcnt(0) per tile -> full HBM latency
//      serialized per tile (the r1/r3 ~5000 cyc/tile mystery). ----
__global__ __launch_bounds__(256, 2)
void attn_fwd_kernel(const float* __restrict__ Qg, const bf16* __restrict__ Kb,
                     const bf16* __restrict__ Vb, const float* __restrict__ Bg,
                     float* __restrict__ Og, float* __restrict__ Sg)
{
    // K tile: [32 kv rows][128 d] bf16, 256B rows, 16-slot XOR swizzle (slot ^ row&15)
    __shared__ __attribute__((aligned(16))) bf16 Kl[3][KVB * DH];   // 3 x 8 KiB
    // V^T tile: 32 rows of 128 elems; row r slot sl holds (d = 4r + sl>>2, kv = (sl&3)*8..+7),
    // 16-slot XOR swizzle (slot ^ row&15) -> uniform b128 bank floor on reads
    __shared__ __attribute__((aligned(16))) bf16 Vl[3][KVB * DH];   // 3 x 8 KiB

    const int tid = threadIdx.x;
    const int w   = tid >> 6;          // 0..3
    const int ln  = tid & 63;
    const int q5  = ln & 31;           // q-col within the wave's 32 rows
    const int hi  = ln >> 5;           // lane-half: co-owner split of each q-row
    const int l15 = ln & 15;

    const int bh = blockIdx.x;
    const int h  = bh & (NH - 1);
    // pi-permuted q-tile: CU pairs (y, y+8) -> tiles (y, 15-y), total work const
    const int qt = (blockIdx.y < 8) ? (int)blockIdx.y : 23 - (int)blockIdx.y;
    const int q0 = qt * QB;
    const int qw = q0 + w * 32;                    // wave's first q row
    const int qr = qw + q5;                        // this lane's q row

    const float slope = exp2f(-0.5f * (float)(h + 1));
    const bf16* kbase = Kb + (size_t)bh * SKV * DH;
    const bf16* vbase = Vb + (size_t)bh * DH * SKV;
    const float* bprow = Bg + (size_t)qr * SKV + 4 * hi;

    // staging: LDS dest linear (global_load_lds), source pre-swizzled (both-sides rule).
    // K: row r slot sp holds global d-slot sp^(r&15) of K[kv0+r].
    // V: row r slot sp holds (d = 4r + sl>>2, kv-slot sl&3), sl = sp^(r&15).
    int ksrc[2], vsrc[2];
#pragma unroll
    for (int i = 0; i < 2; ++i) {
        const int seg = w * 2 + i;                 // 0..7
        const int r   = seg * 4 + (ln >> 4);       // 0..31
        const int sl  = l15 ^ (r & 15);
        ksrc[i] = r * DH + (sl << 3);
        vsrc[i] = (4 * r + (sl >> 2)) * SKV + ((sl & 3) << 3);
    }

    // 4 GLD_LDS per wave per stage -> vmcnt batch size 4
    auto stage = [&](int kv0n, int buf) {
#pragma unroll
        for (int i = 0; i < 2; ++i)
            GLD_LDS(kbase + (size_t)kv0n * DH + ksrc[i], &Kl[buf][(w * 2 + i) * 512]);
#pragma unroll
        for (int i = 0; i < 2; ++i)
            GLD_LDS(vbase + (size_t)kv0n + vsrc[i], &Vl[buf][(w * 2 + i) * 512]);
    };

    const int ntile = (q0 + QB) / KVB;             // block-uniform, >= 4

    // prologue: stage tile 0, then Q-frag loads (consumed immediately),
    // bias for tile 0, then stage tile 1 LAST so vmcnt(4) = "tile-0 batch done,
    // tile-1 batch in flight".
    stage(0, 0);

    // ---- Q fragments (pre-scaled, bf16); MFMA B operand: B[k=hi*8+j][col=q5] ----
    bf16x8 qf[8];
    {
        const float* qrow = Qg + (size_t)bh * SQ * DH + (size_t)qr * DH;
#pragma unroll
        for (int s = 0; s < 8; ++s) {
            const float* qp = qrow + s * 16 + hi * 8;
            float4 a = *(const float4*)qp;
            float4 b = *(const float4*)(qp + 4);
            bf16x8 f;
            f[0]=(bf16)(a.x*SM_SCALE); f[1]=(bf16)(a.y*SM_SCALE);
            f[2]=(bf16)(a.z*SM_SCALE); f[3]=(bf16)(a.w*SM_SCALE);
            f[4]=(bf16)(b.x*SM_SCALE); f[5]=(bf16)(b.y*SM_SCALE);
            f[6]=(bf16)(b.z*SM_SCALE); f[7]=(bf16)(b.w*SM_SCALE);
            qf[s] = f;
        }
    }

    f32x4 bvf[4];                      // bias[qr][kv0 + u*8 + 4*hi + 0..3]
#pragma unroll
    for (int u = 0; u < 4; ++u)
        bvf[u] = *(const f32x4*)(bprow + u * 8);

    stage(KVB, 1);

    // O^T: acc[dt] row = dt*32 + (r&3)+8*(r>>2)+4*hi, col(q) = q5
    f32x16 acc[4];
#pragma unroll
    for (int dt = 0; dt < 4; ++dt)
#pragma unroll
        for (int e = 0; e < 16; ++e) acc[dt][e] = 0.f;
    float denom = 0.f;                 // this lane-half's partial row sum
    float mrow = -INFINITY;

    WAITCNT_VM(4);                     // tile-0 batch done; tile-1 batch in flight
    __builtin_amdgcn_sched_barrier(0);
    __builtin_amdgcn_s_barrier();

    int cur = 0;                       // buffer of tile t (= t % 3)

    for (int t = 0; t < ntile; ++t) {
        const int kv0 = t * KVB;
        // stage tile t+2 into buf (t+2)%3 = (cur+2)%3 (last read in tile t-1;
        // all waves passed the end-of-(t-1) barrier -> safe to overwrite)
        if (t + 2 < ntile) {
            int st = cur - 1; if (st < 0) st = 2;
            stage(kv0 + 2 * KVB, st);
        }

        const bool liveTile = (kv0 <= qw + 31);    // wave-uniform: any visible kv?
        float p[16];
        if (liveTile) {
            // ---- S^T = K (Q*scale)^T : one 32x32 kv-tile, 8 d-steps of 16 ----
            f32x16 s0;
#pragma unroll
            for (int e = 0; e < 16; ++e) s0[e] = 0.f;
            __builtin_amdgcn_s_setprio(1);
#pragma unroll
            for (int s = 0; s < 8; ++s) {
                const int sl = (((2 * s + hi) ^ l15) << 3);
                bf16x8 k0 = *(const bf16x8*)&Kl[cur][q5 * DH + sl];
                s0 = __builtin_amdgcn_mfma_f32_32x32x16_bf16(k0, qf[s], s0, 0, 0, 0);
            }
            __builtin_amdgcn_s_setprio(0);

            // lane holds S for q=qr, kv = kv0 + 8u + v + 4*hi  (r = 4u+v)
            const int dq2 = qr - kv0 - 4 * hi;       // visible iff koff <= dq2
            const float base2 = slope * (float)(-dq2);
            const bool needMask = (kv0 + KVB - 1 > qw);
            if (needMask) {
#pragma unroll
                for (int r = 0; r < 16; ++r) {
                    const int u = r >> 2, v = r & 3;
                    const int koff = 8 * u + v;
                    float x = s0[r] + bvf[u][v] + fmaf(slope, (float)koff, base2);
                    p[r] = (koff > dq2) ? -INFINITY : x;
                }
            } else {
#pragma unroll
                for (int r = 0; r < 16; ++r) {
                    const int u = r >> 2, v = r & 3;
                    p[r] = s0[r] + bvf[u][v] + fmaf(slope, (float)(8 * u + v), base2);
                }
            }

            // row max: in-lane tree + one cross-half shuffle (co-owner lane l^32)
            float mt[4];
#pragma unroll
            for (int r = 0; r < 4; ++r)
                mt[r] = fmaxf(fmaxf(p[r], p[r + 4]), fmaxf(p[r + 8], p[r + 12]));
            float mx = fmaxf(fmaxf(mt[0], mt[1]), fmaxf(mt[2], mt[3]));
            mx = fmaxf(mx, __shfl_xor(mx, 32));

            // T13 defer-max
            if (__any(mx > mrow + DEFER_THR)) {
                const float mn = fmaxf(mrow, mx);
                const float al = exp2f((mrow - mn) * LOG2E);
                mrow = mn;
#pragma unroll
                for (int dt = 0; dt < 4; ++dt)
#pragma unroll
                    for (int e = 0; e < 16; ++e) acc[dt][e] *= al;
                denom *= al;
            }

#pragma unroll
            for (int r = 0; r < 16; ++r)
                p[r] = exp2f((p[r] - mrow) * LOG2E);

            float st4[4];
#pragma unroll
            for (int r = 0; r < 4; ++r)
                st4[r] = (p[r] + p[r + 4]) + (p[r + 8] + p[r + 12]);
            denom += (st4[0] + st4[1]) + (st4[2] + st4[3]);
        }

        // bias prefetch for next tile (hidden under PV + next QK)
        if (t + 1 < ntile) {
#pragma unroll
            for (int u = 0; u < 4; ++u)
                bvf[u] = *(const f32x4*)(bprow + (kv0 + KVB) + u * 8);
        }

        if (liveTile) {
            // ---- PV: O^T += V^T P^T. P^T B-frag assembled in-register:
            // cvt_pk packs own-half kv pairs; permlane32_swap exchanges with co-owner.
            __builtin_amdgcn_s_setprio(1);
#pragma unroll
            for (int s2 = 0; s2 < 2; ++s2) {          // kv steps of 16
                const int r0 = s2 * 8;
                unsigned x1 = cvt_pk_bf16(p[r0 + 0], p[r0 + 1]);
                unsigned x2 = cvt_pk_bf16(p[r0 + 2], p[r0 + 3]);
                unsigned y1 = cvt_pk_bf16(p[r0 + 4], p[r0 + 5]);
                unsigned y2 = cvt_pk_bf16(p[r0 + 6], p[r0 + 7]);
                permswap(x1, y1);
                permswap(x2, y2);
                u32x4 pw; pw[0] = x1; pw[1] = x2; pw[2] = y1; pw[3] = y2;
                const bf16x8 pb = __builtin_bit_cast(bf16x8, pw);
#pragma unroll
                for (int dt = 0; dt < 4; ++dt) {
                    const int vr  = dt * 8 + (q5 >> 2);
                    const int vsl = ((((q5 & 3) << 2) | (2 * s2 + hi)) ^ (vr & 15)) << 3;
                    bf16x8 vb = *(const bf16x8*)&Vl[cur][vr * DH + vsl];
                    acc[dt] = __builtin_amdgcn_mfma_f32_32x32x16_bf16(vb, pb, acc[dt], 0, 0, 0);
                }
            }
            __builtin_amdgcn_s_setprio(0);
        }

        // end-of-tile handoff: force batch t+1 complete, keep newer ops in
        // flight (stage t+2 batch [4] + bias loads [4] when present).
        if (t + 1 < ntile) {
            if (t + 2 < ntile) { WAITCNT_VM(8); }
            else              { WAITCNT_VM(4); }
            __builtin_amdgcn_sched_barrier(0);
            __builtin_amdgcn_s_barrier();
        }
        cur = (cur == 2) ? 0 : cur + 1;
    }

    // ---- epilogue: combine co-owner halves, normalize, store ----
    {
        const float dtot = denom + __shfl_xor(denom, 32);
        const float inv = 1.0f / dtot;
        float* orow = Og + (size_t)bh * SQ * DH + (size_t)qr * DH;
#pragma unroll
        for (int dt = 0; dt < 4; ++dt)
#pragma unroll
            for (int u = 0; u < 4; ++u) {
                f32x4 o;
                o[0] = acc[dt][4 * u + 0] * inv;
                o[1] = acc[dt][4 * u + 1] * inv;
                o[2] = acc[dt][4 * u + 2] * inv;
                o[3] = acc[dt][4 * u + 3] * inv;
                *(f32x4*)(orow + dt * 32 + u * 8 + hi * 4) = o;
            }
        if (hi == 0)
            Sg[(size_t)bh * SQ + qr] = mrow + logf(dtot);
    }
}

extern "C" void kernel_launch(void* const* d_in, const int* in_sizes, int n_in,
                              void* d_out, int out_size, void* d_ws, size_t ws_size,
                              hipStream_t stream) {
    const float* Q = (const float*)d_in[0];
    const float* K = (const float*)d_in[1];
    const float* V = (const float*)d_in[2];
    const float* B = (const float*)d_in[3];
    float* O     = (float*)d_out;
    float* Stats = O + (size_t)NB * NH * SQ * DH;

    const size_t nkv = (size_t)NB * NH * SKV * DH;
    bf16* Kb = (bf16*)d_ws;
    bf16* Vt = Kb + nkv;

    cvt_k_kernel<<<(int)(nkv / (256 * 8)), 256, 0, stream>>>(K, Kb);
    tr_v_kernel<<<dim3(64, NB * NH), 256, 0, stream>>>(V, Vt);

    dim3 grid(NB * NH, SQ / QB);   // x = bh (CU pairing pairs y,y+8 -> balanced)
    attn_fwd_kernel<<<grid, 256, 0, stream>>>(Q, Kb, Vt, B, O, Stats);
}

// Round 5
// 117.043 us; speedup vs baseline: 1.3846x; 1.3846x over previous
//
#include <hip/hip_runtime.h>
#include <hip/hip_bf16.h>
#include <math.h>

typedef __bf16 bf16;
typedef __attribute__((ext_vector_type(8))) __bf16 bf16x8;
typedef __attribute__((ext_vector_type(4))) __bf16 bf16x4;
typedef __attribute__((ext_vector_type(4))) float f32x4;
typedef __attribute__((ext_vector_type(16))) float f32x16;
typedef __attribute__((ext_vector_type(4))) unsigned int u32x4;

constexpr int NB = 2, NH = 16, SQ = 2048, SKV = 2048, DH = 128;
constexpr int QB = 128, KVB = 32;
constexpr float SM_SCALE = 0.08838834764831845f;  // 1/sqrt(128)
constexpr float LOG2E = 1.4426950408889634f;
constexpr float DEFER_THR = 7.0f;                 // T13: p bounded by e^7

#define GLD_LDS(g, l) __builtin_amdgcn_global_load_lds( \
    (const __attribute__((address_space(1))) void*)(g), \
    (__attribute__((address_space(3))) void*)(l), 16, 0, 0)

__device__ __forceinline__ unsigned cvt_pk_bf16(float lo, float hi) {
    unsigned r;
    asm("v_cvt_pk_bf16_f32 %0, %1, %2" : "=v"(r) : "v"(lo), "v"(hi));
    return r;
}
// new a[32:63] = old b[0:31]; new b[0:31] = old a[32:63]
__device__ __forceinline__ void permswap(unsigned &a, unsigned &b) {
    asm("v_permlane32_swap_b32 %0, %1" : "+v"(a), "+v"(b));
}

// ---- pre-pass 1: K fp32 -> bf16, layout unchanged [bh][skv][d] ----
__global__ __launch_bounds__(256)
void cvt_k_kernel(const float* __restrict__ src, bf16* __restrict__ dst) {
    const size_t i = ((size_t)blockIdx.x * 256 + threadIdx.x) * 8;
    float4 a = *(const float4*)(src + i);
    float4 b = *(const float4*)(src + i + 4);
    bf16x8 f;
    f[0]=(bf16)a.x; f[1]=(bf16)a.y; f[2]=(bf16)a.z; f[3]=(bf16)a.w;
    f[4]=(bf16)b.x; f[5]=(bf16)b.y; f[6]=(bf16)b.z; f[7]=(bf16)b.w;
    *(bf16x8*)(dst + i) = f;
}

// ---- pre-pass 2: V fp32 [bh][skv][d] -> bf16 transposed [bh][d][skv] ----
__global__ __launch_bounds__(256)
void tr_v_kernel(const float* __restrict__ src, bf16* __restrict__ dst) {
    __shared__ float Tl[64][65];
    const int bh  = blockIdx.y;
    const int kv0 = (int)(blockIdx.x >> 1) * 64;
    const int d0  = (int)(blockIdx.x & 1) * 64;
    const int t   = threadIdx.x;
    const float* sp = src + (size_t)bh * SQ * DH;
#pragma unroll
    for (int i = 0; i < 4; ++i) {
        const int row = i * 16 + (t >> 4);
        const int c4  = (t & 15) * 4;
        *(float4*)&Tl[row][c4] = *(const float4*)(sp + (size_t)(kv0 + row) * DH + d0 + c4);
    }
    __syncthreads();
    bf16* dp = dst + (size_t)bh * DH * SKV;
#pragma unroll
    for (int i = 0; i < 4; ++i) {
        const int d  = i * 16 + (t >> 4);
        const int k4 = (t & 15) * 4;
        bf16x4 o;
        o[0]=(bf16)Tl[k4+0][d]; o[1]=(bf16)Tl[k4+1][d];
        o[2]=(bf16)Tl[k4+2][d]; o[3]=(bf16)Tl[k4+3][d];
        *(bf16x4*)(dp + (size_t)(d0 + d) * SKV + kv0 + k4) = o;
    }
}

// ---- main attention kernel: 32-row waves (32x32x16 MFMA), swapped-QK,
//      in-register P via cvt_pk + permlane32_swap.
//      THIS ROUND: 8 waves = 4 row-groups x 2 KV-PARITIES. Parity p handles
//      kv tiles t===p (mod 2); the two parities compute DIFFERENT tiles
//      concurrently each iteration (block consumes 2 tiles/iter), restoring
//      4096 waves total = 4 waves/SIMD (r0-level TLP) while keeping the
//      conflict-free 32x32 layouts. Private (m,l,acc) per parity; merged
//      once through LDS at the epilogue (lane-aligned, exact f32 math).
//      Plain __syncthreads (r4's counted-vmcnt graft measured negative). ----
__global__ __launch_bounds__(512, 2)
void attn_fwd_kernel(const float* __restrict__ Qg, const bf16* __restrict__ Kb,
                     const bf16* __restrict__ Vb, const float* __restrict__ Bg,
                     float* __restrict__ Og, float* __restrict__ Sg)
{
    // 0..32KB: K bufs [4][32*128]; 32..64KB: V bufs [4][32*128]
    // epilogue alias: 0..64KB O-merge [4 rg][16 chunk][64 ln][4 f32],
    //                 64..65KB m, 65..66KB l
    __shared__ __attribute__((aligned(16))) char smem[67584];
    bf16* const KlB = (bf16*)smem;
    bf16* const VlB = (bf16*)(smem + 32768);
    float* const Om = (float*)smem;
    float* const Mm = (float*)(smem + 65536);
    float* const Lm = (float*)(smem + 65536 + 1024);

    const int tid = threadIdx.x;
    const int w   = tid >> 6;          // 0..7
    const int rg  = w & 3;             // row-group
    const int par = w >> 2;            // kv parity
    const int ln  = tid & 63;
    const int q5  = ln & 31;           // q-col within the wave's 32 rows
    const int hi  = ln >> 5;           // lane-half: co-owner split of each q-row
    const int l15 = ln & 15;

    const int bh = blockIdx.x;
    const int h  = bh & (NH - 1);
    // pi-permuted q-tile: CU pairs (y, y+8) -> tiles (y, 15-y), total work const
    const int qt = (blockIdx.y < 8) ? (int)blockIdx.y : 23 - (int)blockIdx.y;
    const int q0 = qt * QB;
    const int qw = q0 + rg * 32;                   // wave's first q row
    const int qr = qw + q5;                        // this lane's q row

    const float slope = exp2f(-0.5f * (float)(h + 1));
    const bf16* kbase = Kb + (size_t)bh * SKV * DH;
    const bf16* vbase = Vb + (size_t)bh * DH * SKV;
    const float* bprow = Bg + (size_t)qr * SKV + 4 * hi;

    // staging: LDS dest linear (global_load_lds), source pre-swizzled.
    // seg = w (8 segments of 1KB each for K and V per 8KB tile).
    // K: row r slot sp holds global d-slot sp^(r&15) of K[kv0+r].
    // V: row r slot sp holds (d = 4r + sl>>2, kv-slot sl&3), sl = sp^(r&15).
    const int sr  = w * 4 + (ln >> 4);             // 0..31
    const int ssl = l15 ^ (sr & 15);
    const int ksrc = sr * DH + (ssl << 3);
    const int vsrc = (4 * sr + (ssl >> 2)) * SKV + ((ssl & 3) << 3);

    auto stage = [&](int kv0n, int buf) {
        GLD_LDS(kbase + (size_t)kv0n * DH + ksrc, KlB + buf * (KVB * DH) + w * 512);
        GLD_LDS(vbase + (size_t)kv0n + vsrc,      VlB + buf * (KVB * DH) + w * 512);
    };

    const int ntile = (q0 + QB) / KVB;             // = 4qt+4, even
    const int niter = ntile >> 1;

    stage(0, 0);
    stage(KVB, 1);

    // ---- Q fragments (pre-scaled, bf16); MFMA B operand: B[k=hi*8+j][col=q5] ----
    bf16x8 qf[8];
    {
        const float* qrow = Qg + (size_t)bh * SQ * DH + (size_t)qr * DH;
#pragma unroll
        for (int s = 0; s < 8; ++s) {
            const float* qp = qrow + s * 16 + hi * 8;
            float4 a = *(const float4*)qp;
            float4 b = *(const float4*)(qp + 4);
            bf16x8 f;
            f[0]=(bf16)(a.x*SM_SCALE); f[1]=(bf16)(a.y*SM_SCALE);
            f[2]=(bf16)(a.z*SM_SCALE); f[3]=(bf16)(a.w*SM_SCALE);
            f[4]=(bf16)(b.x*SM_SCALE); f[5]=(bf16)(b.y*SM_SCALE);
            f[6]=(bf16)(b.z*SM_SCALE); f[7]=(bf16)(b.w*SM_SCALE);
            qf[s] = f;
        }
    }

    f32x4 bvf[4];                      // bias[qr][my_kv0 + u*8 + 4*hi + 0..3]
#pragma unroll
    for (int u = 0; u < 4; ++u)
        bvf[u] = *(const f32x4*)(bprow + par * KVB + u * 8);

    // O^T: acc[dt] row = dt*32 + (r&3)+8*(r>>2)+4*hi, col(q) = q5
    f32x16 acc[4];
#pragma unroll
    for (int dt = 0; dt < 4; ++dt)
#pragma unroll
        for (int e = 0; e < 16; ++e) acc[dt][e] = 0.f;
    float denom = 0.f;                 // this lane-half's partial row sum (own parity)
    float mrow = -INFINITY;

    __syncthreads();

    for (int i = 0; i < niter; ++i) {
        const int tA = 2 * i;
        // stage tiles tA+2, tA+3 into bufs (tA+2)&3, (tA+3)&3 (last read in
        // iter i-1; all waves passed that iteration's barrier -> safe)
        if (tA + 2 < ntile) stage((tA + 2) * KVB, (tA + 2) & 3);
        if (tA + 3 < ntile) stage((tA + 3) * KVB, (tA + 3) & 3);

        const int myt = tA + par;                  // this parity's tile
        const int kv0 = myt * KVB;
        const bf16* Kc = KlB + (myt & 3) * (KVB * DH);
        const bf16* Vc = VlB + (myt & 3) * (KVB * DH);
        const bool live = (kv0 <= qw + 31);        // wave-uniform
        float p[16];
        if (live) {
            // ---- S^T = K (Q*scale)^T : one 32x32 kv-tile, 8 d-steps of 16 ----
            f32x16 s0;
#pragma unroll
            for (int e = 0; e < 16; ++e) s0[e] = 0.f;
            __builtin_amdgcn_s_setprio(1);
#pragma unroll
            for (int s = 0; s < 8; ++s) {
                const int sl = (((2 * s + hi) ^ l15) << 3);
                bf16x8 k0 = *(const bf16x8*)&Kc[q5 * DH + sl];
                s0 = __builtin_amdgcn_mfma_f32_32x32x16_bf16(k0, qf[s], s0, 0, 0, 0);
            }
            __builtin_amdgcn_s_setprio(0);

            // lane holds S for q=qr, kv = kv0 + 8u + v + 4*hi  (r = 4u+v)
            const int dq2 = qr - kv0 - 4 * hi;     // visible iff koff <= dq2
            const float base2 = slope * (float)(-dq2);
            const bool needMask = (kv0 + KVB - 1 > qw);
            if (needMask) {
#pragma unroll
                for (int r = 0; r < 16; ++r) {
                    const int u = r >> 2, v = r & 3;
                    const int koff = 8 * u + v;
                    float x = s0[r] + bvf[u][v] + fmaf(slope, (float)koff, base2);
                    p[r] = (koff > dq2) ? -INFINITY : x;
                }
            } else {
#pragma unroll
                for (int r = 0; r < 16; ++r) {
                    const int u = r >> 2, v = r & 3;
                    p[r] = s0[r] + bvf[u][v] + fmaf(slope, (float)(8 * u + v), base2);
                }
            }

            // row max: in-lane tree + one cross-half shuffle (co-owner lane l^32)
            float mt[4];
#pragma unroll
            for (int r = 0; r < 4; ++r)
                mt[r] = fmaxf(fmaxf(p[r], p[r + 4]), fmaxf(p[r + 8], p[r + 12]));
            float mx = fmaxf(fmaxf(mt[0], mt[1]), fmaxf(mt[2], mt[3]));
            mx = fmaxf(mx, __shfl_xor(mx, 32));

            // T13 defer-max
            if (__any(mx > mrow + DEFER_THR)) {
                const float mn = fmaxf(mrow, mx);
                const float al = exp2f((mrow - mn) * LOG2E);
                mrow = mn;
#pragma unroll
                for (int dt = 0; dt < 4; ++dt)
#pragma unroll
                    for (int e = 0; e < 16; ++e) acc[dt][e] *= al;
                denom *= al;
            }

#pragma unroll
            for (int r = 0; r < 16; ++r)
                p[r] = exp2f((p[r] - mrow) * LOG2E);

            float st4[4];
#pragma unroll
            for (int r = 0; r < 4; ++r)
                st4[r] = (p[r] + p[r + 4]) + (p[r + 8] + p[r + 12]);
            denom += (st4[0] + st4[1]) + (st4[2] + st4[3]);
        }

        // bias prefetch for this parity's next tile (t+2)
        if (myt + 2 < ntile) {
#pragma unroll
            for (int u = 0; u < 4; ++u)
                bvf[u] = *(const f32x4*)(bprow + (kv0 + 2 * KVB) + u * 8);
        }

        if (live) {
            // ---- PV: O^T += V^T P^T. P^T B-frag assembled in-register:
            // cvt_pk packs own-half kv pairs; permlane32_swap exchanges with co-owner.
            __builtin_amdgcn_s_setprio(1);
#pragma unroll
            for (int s2 = 0; s2 < 2; ++s2) {          // kv steps of 16
                const int r0 = s2 * 8;
                unsigned x1 = cvt_pk_bf16(p[r0 + 0], p[r0 + 1]);
                unsigned x2 = cvt_pk_bf16(p[r0 + 2], p[r0 + 3]);
                unsigned y1 = cvt_pk_bf16(p[r0 + 4], p[r0 + 5]);
                unsigned y2 = cvt_pk_bf16(p[r0 + 6], p[r0 + 7]);
                permswap(x1, y1);
                permswap(x2, y2);
                u32x4 pw; pw[0] = x1; pw[1] = x2; pw[2] = y1; pw[3] = y2;
                const bf16x8 pb = __builtin_bit_cast(bf16x8, pw);
#pragma unroll
                for (int dt = 0; dt < 4; ++dt) {
                    const int vr  = dt * 8 + (q5 >> 2);
                    const int vsl = ((((q5 & 3) << 2) | (2 * s2 + hi)) ^ (vr & 15)) << 3;
                    bf16x8 vb = *(const bf16x8*)&Vc[vr * DH + vsl];
                    acc[dt] = __builtin_amdgcn_mfma_f32_32x32x16_bf16(vb, pb, acc[dt], 0, 0, 0);
                }
            }
            __builtin_amdgcn_s_setprio(0);
        }

        __syncthreads();  // drains own staging vmcnt + 2-tile buffer handoff
    }

    // ---- epilogue: parity merge via LDS (aliases staging; all staging
    //      drained by the final loop barrier), then normalize + store ----
    if (par == 1) {
        Mm[rg * 64 + ln] = mrow;
        Lm[rg * 64 + ln] = denom;
#pragma unroll
        for (int dt = 0; dt < 4; ++dt)
#pragma unroll
            for (int u = 0; u < 4; ++u) {
                f32x4 o;
                o[0] = acc[dt][4 * u + 0];
                o[1] = acc[dt][4 * u + 1];
                o[2] = acc[dt][4 * u + 2];
                o[3] = acc[dt][4 * u + 3];
                *(f32x4*)&Om[(((rg * 4 + dt) * 4 + u) * 64 + ln) * 4] = o;
            }
    }
    __syncthreads();
    if (par == 0) {
        const float m1 = Mm[rg * 64 + ln];
        const float l1 = Lm[rg * 64 + ln];
        const float m  = fmaxf(mrow, m1);
        const float a0 = exp2f((mrow - m) * LOG2E);
        const float a1 = exp2f((m1 - m) * LOG2E);
        const float dme = a0 * denom + a1 * l1;
        const float dtot = dme + __shfl_xor(dme, 32);
        const float inv = 1.0f / dtot;
        float* orow = Og + (size_t)bh * SQ * DH + (size_t)qr * DH;
#pragma unroll
        for (int dt = 0; dt < 4; ++dt)
#pragma unroll
            for (int u = 0; u < 4; ++u) {
                f32x4 o1 = *(const f32x4*)&Om[(((rg * 4 + dt) * 4 + u) * 64 + ln) * 4];
                f32x4 o;
                o[0] = (a0 * acc[dt][4 * u + 0] + a1 * o1[0]) * inv;
                o[1] = (a0 * acc[dt][4 * u + 1] + a1 * o1[1]) * inv;
                o[2] = (a0 * acc[dt][4 * u + 2] + a1 * o1[2]) * inv;
                o[3] = (a0 * acc[dt][4 * u + 3] + a1 * o1[3]) * inv;
                *(f32x4*)(orow + dt * 32 + u * 8 + hi * 4) = o;
            }
        if (hi == 0)
            Sg[(size_t)bh * SQ + qr] = m + logf(dtot);
    }
}

extern "C" void kernel_launch(void* const* d_in, const int* in_sizes, int n_in,
                              void* d_out, int out_size, void* d_ws, size_t ws_size,
                              hipStream_t stream) {
    const float* Q = (const float*)d_in[0];
    const float* K = (const float*)d_in[1];
    const float* V = (const float*)d_in[2];
    const float* B = (const float*)d_in[3];
    float* O     = (float*)d_out;
    float* Stats = O + (size_t)NB * NH * SQ * DH;

    const size_t nkv = (size_t)NB * NH * SKV * DH;
    bf16* Kb = (bf16*)d_ws;
    bf16* Vt = Kb + nkv;

    cvt_k_kernel<<<(int)(nkv / (256 * 8)), 256, 0, stream>>>(K, Kb);
    tr_v_kernel<<<dim3(64, NB * NH), 256, 0, stream>>>(V, Vt);

    dim3 grid(NB * NH, SQ / QB);   // x = bh (CU pairing pairs y,y+8 -> balanced)
    attn_fwd_kernel<<<grid, 512, 0, stream>>>(Q, Kb, Vt, B, O, Stats);
}